// Round 3
// baseline (1948.946 us; speedup 1.0000x reference)
//
#include <hip/hip_runtime.h>

#define NN 100000
#define FIN 512
#define H1D 64
#define H2D 128
#define CD 40
#define BNEPS 1e-5f

#define BSHIFT 8
#define NB 391          // ceil(NN / 256)

// ---------------- graph preprocessing: bucketed CSR build ----------------

// Pass A: coarse histogram of edges into NB buckets (dst>>8), LDS-staged
__global__ __launch_bounds__(256) void bhist_k(const int* __restrict__ dst, int E,
                                               int* __restrict__ bcount) {
    __shared__ int h[NB];
    for (int i = threadIdx.x; i < NB; i += 256) h[i] = 0;
    __syncthreads();
    int i = blockIdx.x * blockDim.x + threadIdx.x;
    int st = gridDim.x * blockDim.x;
    for (; i < E; i += st) atomicAdd(&h[dst[i] >> BSHIFT], 1);
    __syncthreads();
    for (int j = threadIdx.x; j < NB; j += 256)
        if (h[j]) atomicAdd(&bcount[j], h[j]);
}

// Pass B: exclusive scan over NB bucket counts (single block)
__global__ __launch_bounds__(512) void bscan_k(const int* __restrict__ bcount,
                                               int* __restrict__ bstart,
                                               int* __restrict__ bcursor) {
    __shared__ int sh[NB];
    int tid = threadIdx.x;
    if (tid < NB) sh[tid] = bcount[tid];
    __syncthreads();
    for (int off = 1; off < NB; off <<= 1) {
        int v = (tid < NB && tid >= off) ? sh[tid - off] : 0;
        __syncthreads();
        if (tid < NB) sh[tid] += v;
        __syncthreads();
    }
    if (tid < NB) {
        int s = tid ? sh[tid - 1] : 0;
        bstart[tid] = s;
        bcursor[tid] = s;
    }
    if (tid == 0) bstart[NB] = sh[NB - 1];
}

// Pass C: scatter (src,dst) pairs into bucket-contiguous regions of ebuf
__global__ __launch_bounds__(256) void bscatter_k(const int* __restrict__ src,
                                                  const int* __restrict__ dst, int E,
                                                  int* __restrict__ bcursor,
                                                  int2* __restrict__ ebuf) {
    int i = blockIdx.x * blockDim.x + threadIdx.x;
    int st = gridDim.x * blockDim.x;
    for (; i < E; i += st) {
        int d = dst[i];
        int b = d >> BSHIFT;
        int pos = atomicAdd(&bcursor[b], 1);
        ebuf[pos] = make_int2(src[i], d);
    }
}

// Pass D: per-bucket exact CSR + rowstart + dinv (one workgroup per bucket)
__global__ __launch_bounds__(256) void bcsr_k(const int2* __restrict__ ebuf,
                                              const int* __restrict__ bstart,
                                              int* __restrict__ rowstart,
                                              float* __restrict__ dinv,
                                              int* __restrict__ csr, int E) {
    __shared__ int ldeg[256];
    __shared__ int loff[256];
    __shared__ int lcur[256];
    int b = blockIdx.x, tid = threadIdx.x;
    int node0 = b << BSHIFT;
    int es = bstart[b], ee = bstart[b + 1];
    ldeg[tid] = 0;
    __syncthreads();
    for (int i = es + tid; i < ee; i += 256) atomicAdd(&ldeg[ebuf[i].y & 255], 1);
    __syncthreads();
    int v = ldeg[tid];
    loff[tid] = v;
    __syncthreads();
    for (int off = 1; off < 256; off <<= 1) {
        int u = (tid >= off) ? loff[tid - off] : 0;
        __syncthreads();
        loff[tid] += u;
        __syncthreads();
    }
    int excl = loff[tid] - v;
    int node = node0 + tid;
    if (node < NN) {
        rowstart[node] = es + excl;
        dinv[node] = rsqrtf((float)(v + 1));
    }
    lcur[tid] = es + excl;
    __syncthreads();
    for (int i = es + tid; i < ee; i += 256) {
        int2 e = ebuf[i];
        int pos = atomicAdd(&lcur[e.y & 255], 1);
        csr[pos] = e.x;
    }
    if (b == 0 && tid == 0) rowstart[NN] = E;
}

// ---------------- GEMM1: t1 = (x @ W1) * dinv ----------------
__global__ __launch_bounds__(256) void gemm1_k(const float* __restrict__ x,
                                               const float* __restrict__ W1,
                                               const float* __restrict__ dinv,
                                               float* __restrict__ t1) {
    __shared__ float sx[32 * 68];
    __shared__ float sw[32 * 68];
    int tid = threadIdx.x;
    int r0 = blockIdx.x * 64;
    int rg = tid >> 4;
    int cg = tid & 15;
    float acc[4][4];
#pragma unroll
    for (int i = 0; i < 4; ++i)
#pragma unroll
        for (int j = 0; j < 4; ++j) acc[i][j] = 0.f;

    for (int kb = 0; kb < FIN; kb += 32) {
        __syncthreads();
#pragma unroll
        for (int i = 0; i < 2; ++i) {
            int q = tid + i * 256;
            int row = q >> 3, k4 = q & 7;
            int grow = r0 + row;
            int gr = grow < NN ? grow : NN - 1;
            float4 v = *(const float4*)(x + (size_t)gr * FIN + kb + k4 * 4);
            sx[(k4 * 4 + 0) * 68 + row] = v.x;
            sx[(k4 * 4 + 1) * 68 + row] = v.y;
            sx[(k4 * 4 + 2) * 68 + row] = v.z;
            sx[(k4 * 4 + 3) * 68 + row] = v.w;
            int kk = q >> 4, c4 = (q & 15) * 4;
            *(float4*)&sw[kk * 68 + c4] = *(const float4*)(W1 + (size_t)(kb + kk) * H1D + c4);
        }
        __syncthreads();
#pragma unroll
        for (int k = 0; k < 32; ++k) {
            float4 a = *(const float4*)&sx[k * 68 + rg * 4];
            float4 b = *(const float4*)&sw[k * 68 + cg * 4];
            acc[0][0] += a.x * b.x; acc[0][1] += a.x * b.y; acc[0][2] += a.x * b.z; acc[0][3] += a.x * b.w;
            acc[1][0] += a.y * b.x; acc[1][1] += a.y * b.y; acc[1][2] += a.y * b.z; acc[1][3] += a.y * b.w;
            acc[2][0] += a.z * b.x; acc[2][1] += a.z * b.y; acc[2][2] += a.z * b.z; acc[2][3] += a.z * b.w;
            acc[3][0] += a.w * b.x; acc[3][1] += a.w * b.y; acc[3][2] += a.w * b.z; acc[3][3] += a.w * b.w;
        }
    }
#pragma unroll
    for (int i = 0; i < 4; ++i) {
        int r = r0 + rg * 4 + i;
        if (r < NN) {
            float dv = dinv[r];
            float4 o = { acc[i][0] * dv, acc[i][1] * dv, acc[i][2] * dv, acc[i][3] * dv };
            *(float4*)&t1[(size_t)r * H1D + cg * 4] = o;
        }
    }
}

// ---------------- aggregation over 64-dim rows, one wave per node ----------------
template <int MODE>
__global__ __launch_bounds__(256) void agg64_k(const float* __restrict__ tin,
                                               float* __restrict__ tout,
                                               const int* __restrict__ rowstart,
                                               const int* __restrict__ csr,
                                               const float* __restrict__ dinv,
                                               const float* __restrict__ g,
                                               const float* __restrict__ bt,
                                               const float* __restrict__ rm,
                                               const float* __restrict__ rv,
                                               const float* __restrict__ b) {
    int wid = (blockIdx.x * blockDim.x + threadIdx.x) >> 6;
    int lane = threadIdx.x & 63;
    if (wid >= NN) return;
    int rs = rowstart[wid], re = rowstart[wid + 1];
    float acc = tin[(size_t)wid * H1D + lane];  // self loop
    int i = rs;
    int n4 = rs + ((re - rs) & ~3);
    for (; i < n4; i += 4) {
        int s0 = csr[i], s1 = csr[i + 1], s2 = csr[i + 2], s3 = csr[i + 3];
        float a0 = tin[(size_t)s0 * H1D + lane];
        float a1 = tin[(size_t)s1 * H1D + lane];
        float a2 = tin[(size_t)s2 * H1D + lane];
        float a3 = tin[(size_t)s3 * H1D + lane];
        acc += (a0 + a1) + (a2 + a3);
    }
    for (; i < re; ++i) acc += tin[(size_t)csr[i] * H1D + lane];
    float dv = dinv[wid];
    float z = acc * dv;
    if (MODE == 1) {
        float sc = g[lane] * rsqrtf(rv[lane] + BNEPS);
        float sv = (b[lane] - rm[lane]) * sc + bt[lane];
        z = fmaxf(z * sc + sv, 0.f) * dv;
    }
    tout[(size_t)wid * H1D + lane] = z;
}

// ---------------- fused GEMM2 + BN2 + ReLU + GEMM3 ----------------
__global__ __launch_bounds__(256) void p2p3_k(const float* __restrict__ u2,
                                              const float* __restrict__ W2,
                                              const float* __restrict__ b2,
                                              const float* __restrict__ W3,
                                              const float* __restrict__ g2,
                                              const float* __restrict__ bt2,
                                              const float* __restrict__ rm2,
                                              const float* __restrict__ rv2,
                                              const float* __restrict__ dinv,
                                              float* __restrict__ g3) {
    __shared__ float sW2[H1D * H2D];
    __shared__ float sW3[H2D * CD];
    __shared__ float sc2[H2D], sh2[H2D];
    int tid = threadIdx.x;
    for (int i = tid; i < H1D * H2D; i += 256) sW2[i] = W2[i];
    for (int i = tid; i < H2D * CD; i += 256) sW3[i] = W3[i];
    if (tid < H2D) {
        float s = g2[tid] * rsqrtf(rv2[tid] + BNEPS);
        sc2[tid] = s;
        sh2[tid] = (b2[tid] - rm2[tid]) * s + bt2[tid];
    }
    __syncthreads();
    int node = blockIdx.x * 256 + tid;
    if (node >= NN) return;
    float u[H1D];
    const float4* up = (const float4*)(u2 + (size_t)node * H1D);
#pragma unroll
    for (int i = 0; i < 16; ++i) {
        float4 v = up[i];
        u[4 * i] = v.x; u[4 * i + 1] = v.y; u[4 * i + 2] = v.z; u[4 * i + 3] = v.w;
    }
    float gacc[CD];
#pragma unroll
    for (int c = 0; c < CD; ++c) gacc[c] = 0.f;
    for (int fc = 0; fc < H2D; fc += 32) {
        float a[32];
#pragma unroll
        for (int j = 0; j < 32; ++j) a[j] = 0.f;
        for (int l = 0; l < H1D; ++l) {
            float ul = u[l];
            const float4* wr = (const float4*)&sW2[l * H2D + fc];
#pragma unroll
            for (int j = 0; j < 8; ++j) {
                float4 w = wr[j];
                a[4 * j]     += ul * w.x;
                a[4 * j + 1] += ul * w.y;
                a[4 * j + 2] += ul * w.z;
                a[4 * j + 3] += ul * w.w;
            }
        }
#pragma unroll
        for (int j = 0; j < 32; ++j) {
            int f = fc + j;
            float h = fmaxf(a[j] * sc2[f] + sh2[f], 0.f);
            const float4* w3r = (const float4*)&sW3[f * CD];
#pragma unroll
            for (int c = 0; c < 10; ++c) {
                float4 w = w3r[c];
                gacc[4 * c]     += h * w.x;
                gacc[4 * c + 1] += h * w.y;
                gacc[4 * c + 2] += h * w.z;
                gacc[4 * c + 3] += h * w.w;
            }
        }
    }
    float dv = dinv[node];
    float* op = g3 + (size_t)node * CD;
#pragma unroll
    for (int c = 0; c < 10; ++c) {
        float4 o = { gacc[4 * c] * dv, gacc[4 * c + 1] * dv, gacc[4 * c + 2] * dv, gacc[4 * c + 3] * dv };
        *(float4*)&op[4 * c] = o;
    }
}

// ---------------- aggregation over 40-dim + bias + log_softmax ----------------
__global__ __launch_bounds__(256) void agg40_k(const float* __restrict__ g3,
                                               const float* __restrict__ b3,
                                               const int* __restrict__ rowstart,
                                               const int* __restrict__ csr,
                                               const float* __restrict__ dinv,
                                               float* __restrict__ out) {
    int wid = (blockIdx.x * blockDim.x + threadIdx.x) >> 6;
    int lane = threadIdx.x & 63;
    if (wid >= NN) return;
    int col = lane < CD ? lane : 0;
    int rs = rowstart[wid], re = rowstart[wid + 1];
    float acc = g3[(size_t)wid * CD + col];  // self loop
    int i = rs;
    int n4 = rs + ((re - rs) & ~3);
    for (; i < n4; i += 4) {
        int s0 = csr[i], s1 = csr[i + 1], s2 = csr[i + 2], s3 = csr[i + 3];
        float a0 = g3[(size_t)s0 * CD + col];
        float a1 = g3[(size_t)s1 * CD + col];
        float a2 = g3[(size_t)s2 * CD + col];
        float a3 = g3[(size_t)s3 * CD + col];
        acc += (a0 + a1) + (a2 + a3);
    }
    for (; i < re; ++i) acc += g3[(size_t)csr[i] * CD + col];
    float dv = dinv[wid];
    float z = (lane < CD) ? (acc * dv + b3[col]) : -1e30f;
    float m = z;
#pragma unroll
    for (int off = 32; off > 0; off >>= 1) m = fmaxf(m, __shfl_xor(m, off));
    float e = (lane < CD) ? __expf(z - m) : 0.f;
    float s = e;
#pragma unroll
    for (int off = 32; off > 0; off >>= 1) s += __shfl_xor(s, off);
    if (lane < CD) out[(size_t)wid * CD + lane] = z - m - __logf(s);
}

// ---------------- launcher ----------------

extern "C" void kernel_launch(void* const* d_in, const int* in_sizes, int n_in,
                              void* d_out, int out_size, void* d_ws, size_t ws_size,
                              hipStream_t stream) {
    (void)n_in; (void)out_size; (void)ws_size;
    const float* x   = (const float*)d_in[0];
    const int*   ei  = (const int*)d_in[1];
    const float* W1  = (const float*)d_in[2];
    const float* b1  = (const float*)d_in[3];
    const float* W2  = (const float*)d_in[4];
    const float* b2  = (const float*)d_in[5];
    const float* W3  = (const float*)d_in[6];
    const float* b3  = (const float*)d_in[7];
    const float* g1  = (const float*)d_in[8];
    const float* bt1 = (const float*)d_in[9];
    const float* rm1 = (const float*)d_in[10];
    const float* rv1 = (const float*)d_in[11];
    const float* g2  = (const float*)d_in[12];
    const float* bt2 = (const float*)d_in[13];
    const float* rm2 = (const float*)d_in[14];
    const float* rv2 = (const float*)d_in[15];
    float* out = (float*)d_out;
    const int E = in_sizes[1] / 2;

    char* w = (char*)d_ws;
    auto alloc = [&](size_t bytes) { char* p = w; w += (bytes + 511) & ~(size_t)511; return p; };
    int*   bcount   = (int*)alloc((size_t)NB * 4);
    int*   bstart   = (int*)alloc((size_t)(NB + 1) * 4);
    int*   bcursor  = (int*)alloc((size_t)NB * 4);
    int*   rowstart = (int*)alloc((size_t)(NN + 1) * 4);
    float* dinv     = (float*)alloc((size_t)NN * 4);
    int*   csr      = (int*)alloc((size_t)E * 4);
    float* t1       = (float*)alloc((size_t)NN * H1D * 4);   // reused as u2; ebuf aliases t1+t2
    float* t2       = (float*)alloc((size_t)NN * H1D * 4);
    float* g3       = (float*)alloc((size_t)NN * CD * 4);
    int2*  ebuf     = (int2*)t1;   // 25.6 MB needed, t1+t2 = 51.2 MB; dead before gemm1 writes t1

    hipMemsetAsync(bcount, 0, (size_t)NB * 4, stream);
    bhist_k<<<512, 256, 0, stream>>>(ei + E, E, bcount);
    bscan_k<<<1, 512, 0, stream>>>(bcount, bstart, bcursor);
    bscatter_k<<<1024, 256, 0, stream>>>(ei, ei + E, E, bcursor, ebuf);
    bcsr_k<<<NB, 256, 0, stream>>>(ebuf, bstart, rowstart, dinv, csr, E);
    gemm1_k<<<(NN + 63) / 64, 256, 0, stream>>>(x, W1, dinv, t1);
    agg64_k<1><<<(NN + 3) / 4, 256, 0, stream>>>(t1, t2, rowstart, csr, dinv, g1, bt1, rm1, rv1, b1);
    agg64_k<2><<<(NN + 3) / 4, 256, 0, stream>>>(t2, t1, rowstart, csr, dinv, nullptr, nullptr, nullptr, nullptr, nullptr);
    p2p3_k<<<(NN + 255) / 256, 256, 0, stream>>>(t1, W2, b2, W3, g2, bt2, rm2, rv2, dinv, g3);
    agg40_k<<<(NN + 3) / 4, 256, 0, stream>>>(g3, b3, rowstart, csr, dinv, out);
}

// Round 4
// 900.027 us; speedup vs baseline: 2.1654x; 2.1654x over previous
//
#include <hip/hip_runtime.h>

#define NN 100000
#define FIN 512
#define H1D 64
#define H2D 128
#define CD 40
#define BNEPS 1e-5f

#define BSHIFT 9
#define BSZ 512
#define NB 196          // ceil(NN / 512)
#define CHUNK 8192      // edges per scatter block

// ---------------- graph preprocessing: bucketed CSR build ----------------

// Pass A: coarse histogram of edges into NB buckets (dst>>9), LDS-staged
__global__ __launch_bounds__(256) void bhist_k(const int* __restrict__ dst, int E,
                                               int* __restrict__ bcount) {
    __shared__ int h[NB];
    for (int i = threadIdx.x; i < NB; i += 256) h[i] = 0;
    __syncthreads();
    int i = blockIdx.x * blockDim.x + threadIdx.x;
    int st = gridDim.x * blockDim.x;
    for (; i < E; i += st) atomicAdd(&h[dst[i] >> BSHIFT], 1);
    __syncthreads();
    for (int j = threadIdx.x; j < NB; j += 256)
        if (h[j]) atomicAdd(&bcount[j], h[j]);
}

// Pass B: exclusive scan over NB bucket counts (single block)
__global__ __launch_bounds__(256) void bscan_k(const int* __restrict__ bcount,
                                               int* __restrict__ bstart,
                                               int* __restrict__ bcursor) {
    __shared__ int sh[NB];
    int tid = threadIdx.x;
    if (tid < NB) sh[tid] = bcount[tid];
    __syncthreads();
    for (int off = 1; off < NB; off <<= 1) {
        int v = (tid < NB && tid >= off) ? sh[tid - off] : 0;
        __syncthreads();
        if (tid < NB) sh[tid] += v;
        __syncthreads();
    }
    if (tid < NB) {
        int s = tid ? sh[tid - 1] : 0;
        bstart[tid] = s;
        bcursor[tid] = s;
    }
    if (tid == 0) bstart[NB] = sh[NB - 1];
}

// Pass C: block-local binning scatter. Each block: LDS histogram of its CHUNK,
// ONE global atomicAdd per non-empty bucket to reserve ranges, bin packed
// (src<<9 | dst&511) records into LDS, then coalesced per-bucket wave copies out.
__global__ __launch_bounds__(256) void bscatter_k(const int* __restrict__ src,
                                                  const int* __restrict__ dst, int E,
                                                  int* __restrict__ bcursor,
                                                  int* __restrict__ ebuf) {
    __shared__ int hist[NB];
    __shared__ int loff[NB];
    __shared__ int lcur[NB];
    __shared__ int gbase[NB];
    __shared__ int sbuf[CHUNK];
    int tid = threadIdx.x;
    int e0 = blockIdx.x * CHUNK;
    int e1 = e0 + CHUNK; if (e1 > E) e1 = E;

    for (int i = tid; i < NB; i += 256) hist[i] = 0;
    __syncthreads();
    for (int i = e0 + tid; i < e1; i += 256) atomicAdd(&hist[dst[i] >> BSHIFT], 1);
    __syncthreads();
    // exclusive scan of hist -> loff (NB <= 256)
    int v = (tid < NB) ? hist[tid] : 0;
    loff[tid < NB ? tid : 0] = 0;  // placate
    __syncthreads();
    if (tid < NB) loff[tid] = v;
    __syncthreads();
    for (int off = 1; off < NB; off <<= 1) {
        int u = (tid < NB && tid >= off) ? loff[tid - off] : 0;
        __syncthreads();
        if (tid < NB) loff[tid] += u;
        __syncthreads();
    }
    if (tid < NB) {
        int excl = loff[tid] - v;
        loff[tid] = excl;
        lcur[tid] = excl;
        gbase[tid] = (v > 0) ? atomicAdd(&bcursor[tid], v) : 0;
    }
    __syncthreads();
    // bin into LDS staging
    for (int i = e0 + tid; i < e1; i += 256) {
        int d = dst[i];
        int b = d >> BSHIFT;
        int pos = atomicAdd(&lcur[b], 1);
        sbuf[pos] = (src[i] << BSHIFT) | (d & (BSZ - 1));
    }
    __syncthreads();
    // coalesced copy out, one bucket segment at a time per wave
    int wave = tid >> 6, lane = tid & 63;
    for (int b = wave; b < NB; b += 4) {
        int cnt = (b + 1 < NB ? loff[b + 1] : (e1 - e0)) - loff[b];
        int s0 = loff[b], d0 = gbase[b];
        for (int k = lane; k < cnt; k += 64) ebuf[d0 + k] = sbuf[s0 + k];
    }
}

// Pass D: per-bucket exact CSR + rowstart + dinv (one workgroup per 512-node bucket)
__global__ __launch_bounds__(256) void bcsr_k(const int* __restrict__ ebuf,
                                              const int* __restrict__ bstart,
                                              int* __restrict__ rowstart,
                                              float* __restrict__ dinv,
                                              int* __restrict__ csr, int E) {
    __shared__ int ldeg[BSZ];
    __shared__ int lcur[BSZ];
    __shared__ int s2[256];
    int b = blockIdx.x, tid = threadIdx.x;
    int node0 = b << BSHIFT;
    int es = bstart[b], ee = bstart[b + 1];
    ldeg[tid] = 0; ldeg[tid + 256] = 0;
    __syncthreads();
    for (int i = es + tid; i < ee; i += 256) atomicAdd(&ldeg[ebuf[i] & (BSZ - 1)], 1);
    __syncthreads();
    int a0 = ldeg[2 * tid], a1 = ldeg[2 * tid + 1];
    s2[tid] = a0 + a1;
    __syncthreads();
    for (int off = 1; off < 256; off <<= 1) {
        int u = (tid >= off) ? s2[tid - off] : 0;
        __syncthreads();
        s2[tid] += u;
        __syncthreads();
    }
    int base2 = tid ? s2[tid - 1] : 0;
    int ex0 = base2, ex1 = base2 + a0;
    int n0 = node0 + 2 * tid, n1 = n0 + 1;
    if (n0 < NN) { rowstart[n0] = es + ex0; dinv[n0] = rsqrtf((float)(a0 + 1)); }
    if (n1 < NN) { rowstart[n1] = es + ex1; dinv[n1] = rsqrtf((float)(a1 + 1)); }
    lcur[2 * tid] = es + ex0;
    lcur[2 * tid + 1] = es + ex1;
    __syncthreads();
    for (int i = es + tid; i < ee; i += 256) {
        int e = ebuf[i];
        int pos = atomicAdd(&lcur[e & (BSZ - 1)], 1);
        csr[pos] = ((unsigned)e) >> BSHIFT;
    }
    if (b == 0 && tid == 0) rowstart[NN] = E;
}

// ---------------- GEMM1: t1 = (x @ W1) * dinv ----------------
__global__ __launch_bounds__(256) void gemm1_k(const float* __restrict__ x,
                                               const float* __restrict__ W1,
                                               const float* __restrict__ dinv,
                                               float* __restrict__ t1) {
    __shared__ float sx[32 * 68];
    __shared__ float sw[32 * 68];
    int tid = threadIdx.x;
    int r0 = blockIdx.x * 64;
    int rg = tid >> 4;
    int cg = tid & 15;
    float acc[4][4];
#pragma unroll
    for (int i = 0; i < 4; ++i)
#pragma unroll
        for (int j = 0; j < 4; ++j) acc[i][j] = 0.f;

    for (int kb = 0; kb < FIN; kb += 32) {
        __syncthreads();
#pragma unroll
        for (int i = 0; i < 2; ++i) {
            int q = tid + i * 256;
            int row = q >> 3, k4 = q & 7;
            int grow = r0 + row;
            int gr = grow < NN ? grow : NN - 1;
            float4 v = *(const float4*)(x + (size_t)gr * FIN + kb + k4 * 4);
            sx[(k4 * 4 + 0) * 68 + row] = v.x;
            sx[(k4 * 4 + 1) * 68 + row] = v.y;
            sx[(k4 * 4 + 2) * 68 + row] = v.z;
            sx[(k4 * 4 + 3) * 68 + row] = v.w;
            int kk = q >> 4, c4 = (q & 15) * 4;
            *(float4*)&sw[kk * 68 + c4] = *(const float4*)(W1 + (size_t)(kb + kk) * H1D + c4);
        }
        __syncthreads();
#pragma unroll
        for (int k = 0; k < 32; ++k) {
            float4 a = *(const float4*)&sx[k * 68 + rg * 4];
            float4 b = *(const float4*)&sw[k * 68 + cg * 4];
            acc[0][0] += a.x * b.x; acc[0][1] += a.x * b.y; acc[0][2] += a.x * b.z; acc[0][3] += a.x * b.w;
            acc[1][0] += a.y * b.x; acc[1][1] += a.y * b.y; acc[1][2] += a.y * b.z; acc[1][3] += a.y * b.w;
            acc[2][0] += a.z * b.x; acc[2][1] += a.z * b.y; acc[2][2] += a.z * b.z; acc[2][3] += a.z * b.w;
            acc[3][0] += a.w * b.x; acc[3][1] += a.w * b.y; acc[3][2] += a.w * b.z; acc[3][3] += a.w * b.w;
        }
    }
#pragma unroll
    for (int i = 0; i < 4; ++i) {
        int r = r0 + rg * 4 + i;
        if (r < NN) {
            float dv = dinv[r];
            float4 o = { acc[i][0] * dv, acc[i][1] * dv, acc[i][2] * dv, acc[i][3] * dv };
            *(float4*)&t1[(size_t)r * H1D + cg * 4] = o;
        }
    }
}

// ---------------- aggregation over 64-dim rows, one wave per node ----------------
template <int MODE>
__global__ __launch_bounds__(256) void agg64_k(const float* __restrict__ tin,
                                               float* __restrict__ tout,
                                               const int* __restrict__ rowstart,
                                               const int* __restrict__ csr,
                                               const float* __restrict__ dinv,
                                               const float* __restrict__ g,
                                               const float* __restrict__ bt,
                                               const float* __restrict__ rm,
                                               const float* __restrict__ rv,
                                               const float* __restrict__ b) {
    int wid = (blockIdx.x * blockDim.x + threadIdx.x) >> 6;
    int lane = threadIdx.x & 63;
    if (wid >= NN) return;
    int rs = rowstart[wid], re = rowstart[wid + 1];
    float acc = tin[(size_t)wid * H1D + lane];  // self loop
    int i = rs;
    int n4 = rs + ((re - rs) & ~3);
    for (; i < n4; i += 4) {
        int s0 = csr[i], s1 = csr[i + 1], s2 = csr[i + 2], s3 = csr[i + 3];
        float a0 = tin[(size_t)s0 * H1D + lane];
        float a1 = tin[(size_t)s1 * H1D + lane];
        float a2 = tin[(size_t)s2 * H1D + lane];
        float a3 = tin[(size_t)s3 * H1D + lane];
        acc += (a0 + a1) + (a2 + a3);
    }
    for (; i < re; ++i) acc += tin[(size_t)csr[i] * H1D + lane];
    float dv = dinv[wid];
    float z = acc * dv;
    if (MODE == 1) {
        float sc = g[lane] * rsqrtf(rv[lane] + BNEPS);
        float sv = (b[lane] - rm[lane]) * sc + bt[lane];
        z = fmaxf(z * sc + sv, 0.f) * dv;
    }
    tout[(size_t)wid * H1D + lane] = z;
}

// ---------------- fused GEMM2 + BN2 + ReLU + GEMM3 ----------------
__global__ __launch_bounds__(256) void p2p3_k(const float* __restrict__ u2,
                                              const float* __restrict__ W2,
                                              const float* __restrict__ b2,
                                              const float* __restrict__ W3,
                                              const float* __restrict__ g2,
                                              const float* __restrict__ bt2,
                                              const float* __restrict__ rm2,
                                              const float* __restrict__ rv2,
                                              const float* __restrict__ dinv,
                                              float* __restrict__ g3) {
    __shared__ float sW2[H1D * H2D];
    __shared__ float sW3[H2D * CD];
    __shared__ float sc2[H2D], sh2[H2D];
    int tid = threadIdx.x;
    for (int i = tid; i < H1D * H2D; i += 256) sW2[i] = W2[i];
    for (int i = tid; i < H2D * CD; i += 256) sW3[i] = W3[i];
    if (tid < H2D) {
        float s = g2[tid] * rsqrtf(rv2[tid] + BNEPS);
        sc2[tid] = s;
        sh2[tid] = (b2[tid] - rm2[tid]) * s + bt2[tid];
    }
    __syncthreads();
    int node = blockIdx.x * 256 + tid;
    if (node >= NN) return;
    float u[H1D];
    const float4* up = (const float4*)(u2 + (size_t)node * H1D);
#pragma unroll
    for (int i = 0; i < 16; ++i) {
        float4 v = up[i];
        u[4 * i] = v.x; u[4 * i + 1] = v.y; u[4 * i + 2] = v.z; u[4 * i + 3] = v.w;
    }
    float gacc[CD];
#pragma unroll
    for (int c = 0; c < CD; ++c) gacc[c] = 0.f;
    for (int fc = 0; fc < H2D; fc += 32) {
        float a[32];
#pragma unroll
        for (int j = 0; j < 32; ++j) a[j] = 0.f;
        for (int l = 0; l < H1D; ++l) {
            float ul = u[l];
            const float4* wr = (const float4*)&sW2[l * H2D + fc];
#pragma unroll
            for (int j = 0; j < 8; ++j) {
                float4 w = wr[j];
                a[4 * j]     += ul * w.x;
                a[4 * j + 1] += ul * w.y;
                a[4 * j + 2] += ul * w.z;
                a[4 * j + 3] += ul * w.w;
            }
        }
#pragma unroll
        for (int j = 0; j < 32; ++j) {
            int f = fc + j;
            float h = fmaxf(a[j] * sc2[f] + sh2[f], 0.f);
            const float4* w3r = (const float4*)&sW3[f * CD];
#pragma unroll
            for (int c = 0; c < 10; ++c) {
                float4 w = w3r[c];
                gacc[4 * c]     += h * w.x;
                gacc[4 * c + 1] += h * w.y;
                gacc[4 * c + 2] += h * w.z;
                gacc[4 * c + 3] += h * w.w;
            }
        }
    }
    float dv = dinv[node];
    float* op = g3 + (size_t)node * CD;
#pragma unroll
    for (int c = 0; c < 10; ++c) {
        float4 o = { gacc[4 * c] * dv, gacc[4 * c + 1] * dv, gacc[4 * c + 2] * dv, gacc[4 * c + 3] * dv };
        *(float4*)&op[4 * c] = o;
    }
}

// ---------------- aggregation over 40-dim + bias + log_softmax ----------------
__global__ __launch_bounds__(256) void agg40_k(const float* __restrict__ g3,
                                               const float* __restrict__ b3,
                                               const int* __restrict__ rowstart,
                                               const int* __restrict__ csr,
                                               const float* __restrict__ dinv,
                                               float* __restrict__ out) {
    int wid = (blockIdx.x * blockDim.x + threadIdx.x) >> 6;
    int lane = threadIdx.x & 63;
    if (wid >= NN) return;
    int col = lane < CD ? lane : 0;
    int rs = rowstart[wid], re = rowstart[wid + 1];
    float acc = g3[(size_t)wid * CD + col];  // self loop
    int i = rs;
    int n4 = rs + ((re - rs) & ~3);
    for (; i < n4; i += 4) {
        int s0 = csr[i], s1 = csr[i + 1], s2 = csr[i + 2], s3 = csr[i + 3];
        float a0 = g3[(size_t)s0 * CD + col];
        float a1 = g3[(size_t)s1 * CD + col];
        float a2 = g3[(size_t)s2 * CD + col];
        float a3 = g3[(size_t)s3 * CD + col];
        acc += (a0 + a1) + (a2 + a3);
    }
    for (; i < re; ++i) acc += g3[(size_t)csr[i] * CD + col];
    float dv = dinv[wid];
    float z = (lane < CD) ? (acc * dv + b3[col]) : -1e30f;
    float m = z;
#pragma unroll
    for (int off = 32; off > 0; off >>= 1) m = fmaxf(m, __shfl_xor(m, off));
    float e = (lane < CD) ? __expf(z - m) : 0.f;
    float s = e;
#pragma unroll
    for (int off = 32; off > 0; off >>= 1) s += __shfl_xor(s, off);
    if (lane < CD) out[(size_t)wid * CD + lane] = z - m - __logf(s);
}

// ---------------- launcher ----------------

extern "C" void kernel_launch(void* const* d_in, const int* in_sizes, int n_in,
                              void* d_out, int out_size, void* d_ws, size_t ws_size,
                              hipStream_t stream) {
    (void)n_in; (void)out_size; (void)ws_size;
    const float* x   = (const float*)d_in[0];
    const int*   ei  = (const int*)d_in[1];
    const float* W1  = (const float*)d_in[2];
    const float* b1  = (const float*)d_in[3];
    const float* W2  = (const float*)d_in[4];
    const float* b2  = (const float*)d_in[5];
    const float* W3  = (const float*)d_in[6];
    const float* b3  = (const float*)d_in[7];
    const float* g1  = (const float*)d_in[8];
    const float* bt1 = (const float*)d_in[9];
    const float* rm1 = (const float*)d_in[10];
    const float* rv1 = (const float*)d_in[11];
    const float* g2  = (const float*)d_in[12];
    const float* bt2 = (const float*)d_in[13];
    const float* rm2 = (const float*)d_in[14];
    const float* rv2 = (const float*)d_in[15];
    float* out = (float*)d_out;
    const int E = in_sizes[1] / 2;

    char* w = (char*)d_ws;
    auto alloc = [&](size_t bytes) { char* p = w; w += (bytes + 511) & ~(size_t)511; return p; };
    int*   bcount   = (int*)alloc((size_t)NB * 4);
    int*   bstart   = (int*)alloc((size_t)(NB + 1) * 4);
    int*   bcursor  = (int*)alloc((size_t)NB * 4);
    int*   rowstart = (int*)alloc((size_t)(NN + 1) * 4);
    float* dinv     = (float*)alloc((size_t)NN * 4);
    int*   csr      = (int*)alloc((size_t)E * 4);
    float* t1       = (float*)alloc((size_t)NN * H1D * 4);   // reused as u2; ebuf aliases t1
    float* t2       = (float*)alloc((size_t)NN * H1D * 4);
    float* g3       = (float*)alloc((size_t)NN * CD * 4);
    int*   ebuf     = (int*)t1;   // 12.8 MB packed records; dead before gemm1 writes t1

    hipMemsetAsync(bcount, 0, (size_t)NB * 4, stream);
    bhist_k<<<512, 256, 0, stream>>>(ei + E, E, bcount);
    bscan_k<<<1, 256, 0, stream>>>(bcount, bstart, bcursor);
    bscatter_k<<<(E + CHUNK - 1) / CHUNK, 256, 0, stream>>>(ei, ei + E, E, bcursor, ebuf);
    bcsr_k<<<NB, 256, 0, stream>>>(ebuf, bstart, rowstart, dinv, csr, E);
    gemm1_k<<<(NN + 63) / 64, 256, 0, stream>>>(x, W1, dinv, t1);
    agg64_k<1><<<(NN + 3) / 4, 256, 0, stream>>>(t1, t2, rowstart, csr, dinv, g1, bt1, rm1, rv1, b1);
    agg64_k<2><<<(NN + 3) / 4, 256, 0, stream>>>(t2, t1, rowstart, csr, dinv, nullptr, nullptr, nullptr, nullptr, nullptr);
    p2p3_k<<<(NN + 255) / 256, 256, 0, stream>>>(t1, W2, b2, W3, g2, bt2, rm2, rv2, dinv, g3);
    agg40_k<<<(NN + 3) / 4, 256, 0, stream>>>(g3, b3, rowstart, csr, dinv, out);
}

// Round 5
// 891.802 us; speedup vs baseline: 2.1854x; 1.0092x over previous
//
#include <hip/hip_runtime.h>

#define NN 100000
#define FIN 512
#define H1D 64
#define H2D 128
#define CD 40
#define GP 64           // g3 padded row (bf16) -> 128B line
#define BNEPS 1e-5f

#define BSHIFT 9
#define BSZ 512
#define NB 196          // ceil(NN / 512)
#define CHUNK 8192      // edges per scatter block

__device__ __forceinline__ float bf2f(ushort u) {
    union { uint i; float f; } v; v.i = ((uint)u) << 16; return v.f;
}
__device__ __forceinline__ ushort f2bf(float f) {
    union { float f; uint i; } v; v.f = f;
    uint x = v.i;
    return (ushort)((x + 0x7fffu + ((x >> 16) & 1u)) >> 16);
}

// ---------------- graph preprocessing: bucketed CSR build ----------------

__global__ __launch_bounds__(256) void bhist_k(const int* __restrict__ dst, int E,
                                               int* __restrict__ bcount) {
    __shared__ int h[NB];
    for (int i = threadIdx.x; i < NB; i += 256) h[i] = 0;
    __syncthreads();
    int i = blockIdx.x * blockDim.x + threadIdx.x;
    int st = gridDim.x * blockDim.x;
    for (; i < E; i += st) atomicAdd(&h[dst[i] >> BSHIFT], 1);
    __syncthreads();
    for (int j = threadIdx.x; j < NB; j += 256)
        if (h[j]) atomicAdd(&bcount[j], h[j]);
}

__global__ __launch_bounds__(256) void bscan_k(const int* __restrict__ bcount,
                                               int* __restrict__ bstart,
                                               int* __restrict__ bcursor) {
    __shared__ int sh[NB];
    int tid = threadIdx.x;
    if (tid < NB) sh[tid] = bcount[tid];
    __syncthreads();
    for (int off = 1; off < NB; off <<= 1) {
        int v = (tid < NB && tid >= off) ? sh[tid - off] : 0;
        __syncthreads();
        if (tid < NB) sh[tid] += v;
        __syncthreads();
    }
    if (tid < NB) {
        int s = tid ? sh[tid - 1] : 0;
        bstart[tid] = s;
        bcursor[tid] = s;
    }
    if (tid == 0) bstart[NB] = sh[NB - 1];
}

__global__ __launch_bounds__(256) void bscatter_k(const int* __restrict__ src,
                                                  const int* __restrict__ dst, int E,
                                                  int* __restrict__ bcursor,
                                                  int* __restrict__ ebuf) {
    __shared__ int hist[NB];
    __shared__ int loff[NB];
    __shared__ int lcur[NB];
    __shared__ int gbase[NB];
    __shared__ int sbuf[CHUNK];
    int tid = threadIdx.x;
    int e0 = blockIdx.x * CHUNK;
    int e1 = e0 + CHUNK; if (e1 > E) e1 = E;

    for (int i = tid; i < NB; i += 256) hist[i] = 0;
    __syncthreads();
    for (int i = e0 + tid; i < e1; i += 256) atomicAdd(&hist[dst[i] >> BSHIFT], 1);
    __syncthreads();
    int v = (tid < NB) ? hist[tid] : 0;
    __syncthreads();
    if (tid < NB) loff[tid] = v;
    __syncthreads();
    for (int off = 1; off < NB; off <<= 1) {
        int u = (tid < NB && tid >= off) ? loff[tid - off] : 0;
        __syncthreads();
        if (tid < NB) loff[tid] += u;
        __syncthreads();
    }
    if (tid < NB) {
        int excl = loff[tid] - v;
        loff[tid] = excl;
        lcur[tid] = excl;
        gbase[tid] = (v > 0) ? atomicAdd(&bcursor[tid], v) : 0;
    }
    __syncthreads();
    for (int i = e0 + tid; i < e1; i += 256) {
        int d = dst[i];
        int b = d >> BSHIFT;
        int pos = atomicAdd(&lcur[b], 1);
        sbuf[pos] = (src[i] << BSHIFT) | (d & (BSZ - 1));
    }
    __syncthreads();
    int wave = tid >> 6, lane = tid & 63;
    for (int b = wave; b < NB; b += 4) {
        int cnt = (b + 1 < NB ? loff[b + 1] : (e1 - e0)) - loff[b];
        int s0 = loff[b], d0 = gbase[b];
        for (int k = lane; k < cnt; k += 64) ebuf[d0 + k] = sbuf[s0 + k];
    }
}

__global__ __launch_bounds__(256) void bcsr_k(const int* __restrict__ ebuf,
                                              const int* __restrict__ bstart,
                                              int* __restrict__ rowstart,
                                              float* __restrict__ dinv,
                                              int* __restrict__ csr, int E) {
    __shared__ int ldeg[BSZ];
    __shared__ int lcur[BSZ];
    __shared__ int s2[256];
    int b = blockIdx.x, tid = threadIdx.x;
    int node0 = b << BSHIFT;
    int es = bstart[b], ee = bstart[b + 1];
    ldeg[tid] = 0; ldeg[tid + 256] = 0;
    __syncthreads();
    for (int i = es + tid; i < ee; i += 256) atomicAdd(&ldeg[ebuf[i] & (BSZ - 1)], 1);
    __syncthreads();
    int a0 = ldeg[2 * tid], a1 = ldeg[2 * tid + 1];
    s2[tid] = a0 + a1;
    __syncthreads();
    for (int off = 1; off < 256; off <<= 1) {
        int u = (tid >= off) ? s2[tid - off] : 0;
        __syncthreads();
        s2[tid] += u;
        __syncthreads();
    }
    int base2 = tid ? s2[tid - 1] : 0;
    int ex0 = base2, ex1 = base2 + a0;
    int n0 = node0 + 2 * tid, n1 = n0 + 1;
    if (n0 < NN) { rowstart[n0] = es + ex0; dinv[n0] = rsqrtf((float)(a0 + 1)); }
    if (n1 < NN) { rowstart[n1] = es + ex1; dinv[n1] = rsqrtf((float)(a1 + 1)); }
    lcur[2 * tid] = es + ex0;
    lcur[2 * tid + 1] = es + ex1;
    __syncthreads();
    for (int i = es + tid; i < ee; i += 256) {
        int e = ebuf[i];
        int pos = atomicAdd(&lcur[e & (BSZ - 1)], 1);
        csr[pos] = ((unsigned)e) >> BSHIFT;
    }
    if (b == 0 && tid == 0) rowstart[NN] = E;
}

// ---------------- GEMM1: t1 = bf16( (x @ W1) * dinv ) ----------------
__global__ __launch_bounds__(256) void gemm1_k(const float* __restrict__ x,
                                               const float* __restrict__ W1,
                                               const float* __restrict__ dinv,
                                               ushort* __restrict__ t1) {
    __shared__ float sx[32 * 68];
    __shared__ float sw[32 * 68];
    int tid = threadIdx.x;
    int r0 = blockIdx.x * 64;
    int rg = tid >> 4;
    int cg = tid & 15;
    float acc[4][4];
#pragma unroll
    for (int i = 0; i < 4; ++i)
#pragma unroll
        for (int j = 0; j < 4; ++j) acc[i][j] = 0.f;

    for (int kb = 0; kb < FIN; kb += 32) {
        __syncthreads();
#pragma unroll
        for (int i = 0; i < 2; ++i) {
            int q = tid + i * 256;
            int row = q >> 3, k4 = q & 7;
            int grow = r0 + row;
            int gr = grow < NN ? grow : NN - 1;
            float4 v = *(const float4*)(x + (size_t)gr * FIN + kb + k4 * 4);
            sx[(k4 * 4 + 0) * 68 + row] = v.x;
            sx[(k4 * 4 + 1) * 68 + row] = v.y;
            sx[(k4 * 4 + 2) * 68 + row] = v.z;
            sx[(k4 * 4 + 3) * 68 + row] = v.w;
            int kk = q >> 4, c4 = (q & 15) * 4;
            *(float4*)&sw[kk * 68 + c4] = *(const float4*)(W1 + (size_t)(kb + kk) * H1D + c4);
        }
        __syncthreads();
#pragma unroll
        for (int k = 0; k < 32; ++k) {
            float4 a = *(const float4*)&sx[k * 68 + rg * 4];
            float4 b = *(const float4*)&sw[k * 68 + cg * 4];
            acc[0][0] += a.x * b.x; acc[0][1] += a.x * b.y; acc[0][2] += a.x * b.z; acc[0][3] += a.x * b.w;
            acc[1][0] += a.y * b.x; acc[1][1] += a.y * b.y; acc[1][2] += a.y * b.z; acc[1][3] += a.y * b.w;
            acc[2][0] += a.z * b.x; acc[2][1] += a.z * b.y; acc[2][2] += a.z * b.z; acc[2][3] += a.z * b.w;
            acc[3][0] += a.w * b.x; acc[3][1] += a.w * b.y; acc[3][2] += a.w * b.z; acc[3][3] += a.w * b.w;
        }
    }
#pragma unroll
    for (int i = 0; i < 4; ++i) {
        int r = r0 + rg * 4 + i;
        if (r < NN) {
            float dv = dinv[r];
            uint2 o;
            o.x = (uint)f2bf(acc[i][0] * dv) | ((uint)f2bf(acc[i][1] * dv) << 16);
            o.y = (uint)f2bf(acc[i][2] * dv) | ((uint)f2bf(acc[i][3] * dv) << 16);
            *(uint2*)&t1[(size_t)r * H1D + cg * 4] = o;
        }
    }
}

// ---------------- aggregation over 64-dim bf16 rows, one wave per node ----------------
template <int MODE>
__global__ __launch_bounds__(256) void agg64_k(const ushort* __restrict__ tin,
                                               ushort* __restrict__ tout,
                                               const int* __restrict__ rowstart,
                                               const int* __restrict__ csr,
                                               const float* __restrict__ dinv,
                                               const float* __restrict__ g,
                                               const float* __restrict__ bt,
                                               const float* __restrict__ rm,
                                               const float* __restrict__ rv,
                                               const float* __restrict__ b) {
    int wid = (blockIdx.x * blockDim.x + threadIdx.x) >> 6;
    int lane = threadIdx.x & 63;
    if (wid >= NN) return;
    int rs = rowstart[wid], re = rowstart[wid + 1];
    float acc = bf2f(tin[(size_t)wid * H1D + lane]);  // self loop
    int i = rs;
    int n4 = rs + ((re - rs) & ~3);
    for (; i < n4; i += 4) {
        int s0 = csr[i], s1 = csr[i + 1], s2 = csr[i + 2], s3 = csr[i + 3];
        float a0 = bf2f(tin[(size_t)s0 * H1D + lane]);
        float a1 = bf2f(tin[(size_t)s1 * H1D + lane]);
        float a2 = bf2f(tin[(size_t)s2 * H1D + lane]);
        float a3 = bf2f(tin[(size_t)s3 * H1D + lane]);
        acc += (a0 + a1) + (a2 + a3);
    }
    for (; i < re; ++i) acc += bf2f(tin[(size_t)csr[i] * H1D + lane]);
    float dv = dinv[wid];
    float z = acc * dv;
    if (MODE == 1) {
        float sc = g[lane] * rsqrtf(rv[lane] + BNEPS);
        float sv = (b[lane] - rm[lane]) * sc + bt[lane];
        z = fmaxf(z * sc + sv, 0.f) * dv;
    }
    tout[(size_t)wid * H1D + lane] = f2bf(z);
}

// ---------------- fused GEMM2 + BN2 + ReLU + GEMM3 (bf16 in, bf16 padded out) ----------------
__global__ __launch_bounds__(256) void p2p3_k(const ushort* __restrict__ u2,
                                              const float* __restrict__ W2,
                                              const float* __restrict__ b2,
                                              const float* __restrict__ W3,
                                              const float* __restrict__ g2,
                                              const float* __restrict__ bt2,
                                              const float* __restrict__ rm2,
                                              const float* __restrict__ rv2,
                                              const float* __restrict__ dinv,
                                              ushort* __restrict__ g3) {
    __shared__ float sW2[H1D * H2D];
    __shared__ float sW3[H2D * CD];
    __shared__ float sc2[H2D], sh2[H2D];
    int tid = threadIdx.x;
    for (int i = tid; i < H1D * H2D; i += 256) sW2[i] = W2[i];
    for (int i = tid; i < H2D * CD; i += 256) sW3[i] = W3[i];
    if (tid < H2D) {
        float s = g2[tid] * rsqrtf(rv2[tid] + BNEPS);
        sc2[tid] = s;
        sh2[tid] = (b2[tid] - rm2[tid]) * s + bt2[tid];
    }
    __syncthreads();
    int node = blockIdx.x * 256 + tid;
    if (node >= NN) return;
    float u[H1D];
    const uint4* up = (const uint4*)(u2 + (size_t)node * H1D);
#pragma unroll
    for (int i = 0; i < 8; ++i) {
        uint4 v = up[i];
        u[8 * i + 0] = bf2f((ushort)(v.x & 0xffff)); u[8 * i + 1] = bf2f((ushort)(v.x >> 16));
        u[8 * i + 2] = bf2f((ushort)(v.y & 0xffff)); u[8 * i + 3] = bf2f((ushort)(v.y >> 16));
        u[8 * i + 4] = bf2f((ushort)(v.z & 0xffff)); u[8 * i + 5] = bf2f((ushort)(v.z >> 16));
        u[8 * i + 6] = bf2f((ushort)(v.w & 0xffff)); u[8 * i + 7] = bf2f((ushort)(v.w >> 16));
    }
    float gacc[CD];
#pragma unroll
    for (int c = 0; c < CD; ++c) gacc[c] = 0.f;
    for (int fc = 0; fc < H2D; fc += 32) {
        float a[32];
#pragma unroll
        for (int j = 0; j < 32; ++j) a[j] = 0.f;
        for (int l = 0; l < H1D; ++l) {
            float ul = u[l];
            const float4* wr = (const float4*)&sW2[l * H2D + fc];
#pragma unroll
            for (int j = 0; j < 8; ++j) {
                float4 w = wr[j];
                a[4 * j]     += ul * w.x;
                a[4 * j + 1] += ul * w.y;
                a[4 * j + 2] += ul * w.z;
                a[4 * j + 3] += ul * w.w;
            }
        }
#pragma unroll
        for (int j = 0; j < 32; ++j) {
            int f = fc + j;
            float h = fmaxf(a[j] * sc2[f] + sh2[f], 0.f);
            const float4* w3r = (const float4*)&sW3[f * CD];
#pragma unroll
            for (int c = 0; c < 10; ++c) {
                float4 w = w3r[c];
                gacc[4 * c]     += h * w.x;
                gacc[4 * c + 1] += h * w.y;
                gacc[4 * c + 2] += h * w.z;
                gacc[4 * c + 3] += h * w.w;
            }
        }
    }
    float dv = dinv[node];
    ushort* op = g3 + (size_t)node * GP;
#pragma unroll
    for (int c = 0; c < 10; ++c) {
        uint pk = (uint)f2bf(gacc[4 * c] * dv) | ((uint)f2bf(gacc[4 * c + 1] * dv) << 16);
        uint pk2 = (uint)f2bf(gacc[4 * c + 2] * dv) | ((uint)f2bf(gacc[4 * c + 3] * dv) << 16);
        *(uint2*)&op[4 * c] = make_uint2(pk, pk2);
    }
}

// ---------------- aggregation over padded 40-dim bf16 + bias + log_softmax ----------------
__global__ __launch_bounds__(256) void agg40_k(const ushort* __restrict__ g3,
                                               const float* __restrict__ b3,
                                               const int* __restrict__ rowstart,
                                               const int* __restrict__ csr,
                                               const float* __restrict__ dinv,
                                               float* __restrict__ out) {
    int wid = (blockIdx.x * blockDim.x + threadIdx.x) >> 6;
    int lane = threadIdx.x & 63;
    if (wid >= NN) return;
    int col = lane < CD ? lane : 0;
    int rs = rowstart[wid], re = rowstart[wid + 1];
    float acc = bf2f(g3[(size_t)wid * GP + col]);  // self loop
    int i = rs;
    int n4 = rs + ((re - rs) & ~3);
    for (; i < n4; i += 4) {
        int s0 = csr[i], s1 = csr[i + 1], s2 = csr[i + 2], s3 = csr[i + 3];
        float a0 = bf2f(g3[(size_t)s0 * GP + col]);
        float a1 = bf2f(g3[(size_t)s1 * GP + col]);
        float a2 = bf2f(g3[(size_t)s2 * GP + col]);
        float a3 = bf2f(g3[(size_t)s3 * GP + col]);
        acc += (a0 + a1) + (a2 + a3);
    }
    for (; i < re; ++i) acc += bf2f(g3[(size_t)csr[i] * GP + col]);
    float dv = dinv[wid];
    float z = (lane < CD) ? (acc * dv + b3[col]) : -1e30f;
    float m = z;
#pragma unroll
    for (int off = 32; off > 0; off >>= 1) m = fmaxf(m, __shfl_xor(m, off));
    float e = (lane < CD) ? __expf(z - m) : 0.f;
    float s = e;
#pragma unroll
    for (int off = 32; off > 0; off >>= 1) s += __shfl_xor(s, off);
    if (lane < CD) out[(size_t)wid * CD + lane] = z - m - __logf(s);
}

// ---------------- launcher ----------------

extern "C" void kernel_launch(void* const* d_in, const int* in_sizes, int n_in,
                              void* d_out, int out_size, void* d_ws, size_t ws_size,
                              hipStream_t stream) {
    (void)n_in; (void)out_size; (void)ws_size;
    const float* x   = (const float*)d_in[0];
    const int*   ei  = (const int*)d_in[1];
    const float* W1  = (const float*)d_in[2];
    const float* b1  = (const float*)d_in[3];
    const float* W2  = (const float*)d_in[4];
    const float* b2  = (const float*)d_in[5];
    const float* W3  = (const float*)d_in[6];
    const float* b3  = (const float*)d_in[7];
    const float* g1  = (const float*)d_in[8];
    const float* bt1 = (const float*)d_in[9];
    const float* rm1 = (const float*)d_in[10];
    const float* rv1 = (const float*)d_in[11];
    const float* g2  = (const float*)d_in[12];
    const float* bt2 = (const float*)d_in[13];
    const float* rm2 = (const float*)d_in[14];
    const float* rv2 = (const float*)d_in[15];
    float* out = (float*)d_out;
    const int E = in_sizes[1] / 2;

    char* w = (char*)d_ws;
    auto alloc = [&](size_t bytes) { char* p = w; w += (bytes + 511) & ~(size_t)511; return p; };
    int*    bcount   = (int*)alloc((size_t)NB * 4);
    int*    bstart   = (int*)alloc((size_t)(NB + 1) * 4);
    int*    bcursor  = (int*)alloc((size_t)NB * 4);
    int*    rowstart = (int*)alloc((size_t)(NN + 1) * 4);
    float*  dinv     = (float*)alloc((size_t)NN * 4);
    int*    csr      = (int*)alloc((size_t)E * 4);
    int*    ebuf     = (int*)alloc((size_t)E * 4);          // packed (src<<9|dst&511)
    ushort* t1       = (ushort*)alloc((size_t)NN * H1D * 2); // bf16; reused as u2
    ushort* t2       = (ushort*)alloc((size_t)NN * H1D * 2); // bf16
    ushort* g3       = (ushort*)alloc((size_t)NN * GP * 2);  // bf16, padded to 64/row

    hipMemsetAsync(bcount, 0, (size_t)NB * 4, stream);
    bhist_k<<<512, 256, 0, stream>>>(ei + E, E, bcount);
    bscan_k<<<1, 256, 0, stream>>>(bcount, bstart, bcursor);
    bscatter_k<<<(E + CHUNK - 1) / CHUNK, 256, 0, stream>>>(ei, ei + E, E, bcursor, ebuf);
    bcsr_k<<<NB, 256, 0, stream>>>(ebuf, bstart, rowstart, dinv, csr, E);
    gemm1_k<<<(NN + 63) / 64, 256, 0, stream>>>(x, W1, dinv, t1);
    agg64_k<1><<<(NN + 3) / 4, 256, 0, stream>>>(t1, t2, rowstart, csr, dinv, g1, bt1, rm1, rv1, b1);
    agg64_k<2><<<(NN + 3) / 4, 256, 0, stream>>>(t2, t1, rowstart, csr, dinv, nullptr, nullptr, nullptr, nullptr, nullptr);
    p2p3_k<<<(NN + 255) / 256, 256, 0, stream>>>(t1, W2, b2, W3, g2, bt2, rm2, rv2, dinv, g3);
    agg40_k<<<(NN + 3) / 4, 256, 0, stream>>>(g3, b3, rowstart, csr, dinv, out);
}

// Round 6
// 851.401 us; speedup vs baseline: 2.2891x; 1.0475x over previous
//
#include <hip/hip_runtime.h>
#include <hip/hip_bf16.h>

#define NN 100000
#define FIN 512
#define H1D 64
#define H2D 128
#define CD 40
#define GP 64           // g3 padded row (bf16) -> one 128B line
#define BNEPS 1e-5f

#define BSHIFT 9
#define BSZ 512
#define NB 196          // ceil(NN / 512)
#define CHUNK 8192      // edges per scatter block

typedef __attribute__((ext_vector_type(8))) short bf16x8;
typedef __attribute__((ext_vector_type(4))) float f32x4;

__device__ __forceinline__ float bf2f(ushort u) {
    union { uint i; float f; } v; v.i = ((uint)u) << 16; return v.f;
}
__device__ __forceinline__ ushort f2bf(float f) {
    union { float f; uint i; } v; v.f = f;
    uint x = v.i;
    return (ushort)((x + 0x7fffu + ((x >> 16) & 1u)) >> 16);
}

// ---------------- graph preprocessing: bucketed CSR build ----------------

__global__ __launch_bounds__(256) void bhist_k(const int* __restrict__ dst, int E,
                                               int* __restrict__ bcount) {
    __shared__ int h[NB];
    for (int i = threadIdx.x; i < NB; i += 256) h[i] = 0;
    __syncthreads();
    int i = blockIdx.x * blockDim.x + threadIdx.x;
    int st = gridDim.x * blockDim.x;
    for (; i < E; i += st) atomicAdd(&h[dst[i] >> BSHIFT], 1);
    __syncthreads();
    for (int j = threadIdx.x; j < NB; j += 256)
        if (h[j]) atomicAdd(&bcount[j], h[j]);
}

__global__ __launch_bounds__(256) void bscan_k(const int* __restrict__ bcount,
                                               int* __restrict__ bstart,
                                               int* __restrict__ bcursor) {
    __shared__ int sh[NB];
    int tid = threadIdx.x;
    if (tid < NB) sh[tid] = bcount[tid];
    __syncthreads();
    for (int off = 1; off < NB; off <<= 1) {
        int v = (tid < NB && tid >= off) ? sh[tid - off] : 0;
        __syncthreads();
        if (tid < NB) sh[tid] += v;
        __syncthreads();
    }
    if (tid < NB) {
        int s = tid ? sh[tid - 1] : 0;
        bstart[tid] = s;
        bcursor[tid] = s;
    }
    if (tid == 0) bstart[NB] = sh[NB - 1];
}

__global__ __launch_bounds__(256) void bscatter_k(const int* __restrict__ src,
                                                  const int* __restrict__ dst, int E,
                                                  int* __restrict__ bcursor,
                                                  int* __restrict__ ebuf) {
    __shared__ int hist[NB];
    __shared__ int loff[NB];
    __shared__ int lcur[NB];
    __shared__ int gbase[NB];
    __shared__ int sbuf[CHUNK];
    int tid = threadIdx.x;
    int e0 = blockIdx.x * CHUNK;
    int e1 = e0 + CHUNK; if (e1 > E) e1 = E;

    for (int i = tid; i < NB; i += 256) hist[i] = 0;
    __syncthreads();
    for (int i = e0 + tid; i < e1; i += 256) atomicAdd(&hist[dst[i] >> BSHIFT], 1);
    __syncthreads();
    int v = (tid < NB) ? hist[tid] : 0;
    __syncthreads();
    if (tid < NB) loff[tid] = v;
    __syncthreads();
    for (int off = 1; off < NB; off <<= 1) {
        int u = (tid < NB && tid >= off) ? loff[tid - off] : 0;
        __syncthreads();
        if (tid < NB) loff[tid] += u;
        __syncthreads();
    }
    if (tid < NB) {
        int excl = loff[tid] - v;
        loff[tid] = excl;
        lcur[tid] = excl;
        gbase[tid] = (v > 0) ? atomicAdd(&bcursor[tid], v) : 0;
    }
    __syncthreads();
    for (int i = e0 + tid; i < e1; i += 256) {
        int d = dst[i];
        int b = d >> BSHIFT;
        int pos = atomicAdd(&lcur[b], 1);
        sbuf[pos] = (src[i] << BSHIFT) | (d & (BSZ - 1));
    }
    __syncthreads();
    int wave = tid >> 6, lane = tid & 63;
    for (int b = wave; b < NB; b += 4) {
        int cnt = (b + 1 < NB ? loff[b + 1] : (e1 - e0)) - loff[b];
        int s0 = loff[b], d0 = gbase[b];
        for (int k = lane; k < cnt; k += 64) ebuf[d0 + k] = sbuf[s0 + k];
    }
}

__global__ __launch_bounds__(256) void bcsr_k(const int* __restrict__ ebuf,
                                              const int* __restrict__ bstart,
                                              int* __restrict__ rowstart,
                                              float* __restrict__ dinv,
                                              int* __restrict__ csr, int E) {
    __shared__ int ldeg[BSZ];
    __shared__ int lcur[BSZ];
    __shared__ int s2[256];
    int b = blockIdx.x, tid = threadIdx.x;
    int node0 = b << BSHIFT;
    int es = bstart[b], ee = bstart[b + 1];
    ldeg[tid] = 0; ldeg[tid + 256] = 0;
    __syncthreads();
    for (int i = es + tid; i < ee; i += 256) atomicAdd(&ldeg[ebuf[i] & (BSZ - 1)], 1);
    __syncthreads();
    int a0 = ldeg[2 * tid], a1 = ldeg[2 * tid + 1];
    s2[tid] = a0 + a1;
    __syncthreads();
    for (int off = 1; off < 256; off <<= 1) {
        int u = (tid >= off) ? s2[tid - off] : 0;
        __syncthreads();
        s2[tid] += u;
        __syncthreads();
    }
    int base2 = tid ? s2[tid - 1] : 0;
    int ex0 = base2, ex1 = base2 + a0;
    int n0 = node0 + 2 * tid, n1 = n0 + 1;
    if (n0 < NN) { rowstart[n0] = es + ex0; dinv[n0] = rsqrtf((float)(a0 + 1)); }
    if (n1 < NN) { rowstart[n1] = es + ex1; dinv[n1] = rsqrtf((float)(a1 + 1)); }
    lcur[2 * tid] = es + ex0;
    lcur[2 * tid + 1] = es + ex1;
    __syncthreads();
    for (int i = es + tid; i < ee; i += 256) {
        int e = ebuf[i];
        int pos = atomicAdd(&lcur[e & (BSZ - 1)], 1);
        csr[pos] = ((unsigned)e) >> BSHIFT;
    }
    if (b == 0 && tid == 0) rowstart[NN] = E;
}

// ---------------- W1 -> bf16 transposed [64][512] ----------------
__global__ __launch_bounds__(256) void w1cvt_k(const float* __restrict__ W1,
                                               ushort* __restrict__ w1t) {
    int i = blockIdx.x * 256 + threadIdx.x;
    if (i < FIN * H1D) {
        int n = i >> 9, k = i & 511;
        w1t[i] = f2bf(W1[k * H1D + n]);
    }
}

// ---------------- GEMM1 (MFMA bf16): t1 = bf16( (x @ W1) * dinv ) ----------------
// block = 256 (4 waves), each wave 16 rows x 64 cols, K=512. W1t staged in LDS.
#define BPAD 520
__global__ __launch_bounds__(256) void gemm1_k(const float* __restrict__ x,
                                               const ushort* __restrict__ w1t,
                                               const float* __restrict__ dinv,
                                               ushort* __restrict__ t1) {
    __shared__ ushort sB[H1D * BPAD];   // 66.5 KB, row pad -> 2-way max conflicts
    int tid = threadIdx.x;
    {
        int row = tid >> 2, seg = tid & 3;
        const uint4* srcp = (const uint4*)(w1t + row * FIN + seg * 128);
        uint4* dstp = (uint4*)(sB + row * BPAD + seg * 128);
#pragma unroll
        for (int j = 0; j < 16; ++j) dstp[j] = srcp[j];
    }
    __syncthreads();
    int wave = tid >> 6, lane = tid & 63;
    int lm = lane & 15, q = lane >> 4;
    int r0 = blockIdx.x * 64 + wave * 16;
    int mrow = r0 + lm;
    int mc = mrow < NN ? mrow : NN - 1;
    const float* ap = x + (size_t)mc * FIN + q * 8;
    const ushort* bp = sB + (size_t)lm * BPAD + q * 8;
    f32x4 acc0 = {0.f, 0.f, 0.f, 0.f}, acc1 = acc0, acc2 = acc0, acc3 = acc0;
#pragma unroll 2
    for (int kb = 0; kb < FIN; kb += 32) {
        float4 a01 = *(const float4*)(ap + kb);
        float4 a23 = *(const float4*)(ap + kb + 4);
        union { bf16x8 v8; __hip_bfloat162 h2[4]; } ua;
        ua.h2[0] = __float22bfloat162_rn(make_float2(a01.x, a01.y));
        ua.h2[1] = __float22bfloat162_rn(make_float2(a01.z, a01.w));
        ua.h2[2] = __float22bfloat162_rn(make_float2(a23.x, a23.y));
        ua.h2[3] = __float22bfloat162_rn(make_float2(a23.z, a23.w));
        bf16x8 b0 = *(const bf16x8*)(bp + kb);
        bf16x8 b1 = *(const bf16x8*)(bp + 16 * BPAD + kb);
        bf16x8 b2 = *(const bf16x8*)(bp + 32 * BPAD + kb);
        bf16x8 b3 = *(const bf16x8*)(bp + 48 * BPAD + kb);
        acc0 = __builtin_amdgcn_mfma_f32_16x16x32_bf16(ua.v8, b0, acc0, 0, 0, 0);
        acc1 = __builtin_amdgcn_mfma_f32_16x16x32_bf16(ua.v8, b1, acc1, 0, 0, 0);
        acc2 = __builtin_amdgcn_mfma_f32_16x16x32_bf16(ua.v8, b2, acc2, 0, 0, 0);
        acc3 = __builtin_amdgcn_mfma_f32_16x16x32_bf16(ua.v8, b3, acc3, 0, 0, 0);
    }
    // C/D: col = lane&15 (within 16-col block), row = q*4 + reg
    int rbase = r0 + q * 4;
#pragma unroll
    for (int r = 0; r < 4; ++r) {
        int row = rbase + r;
        if (row < NN) {
            float dv = dinv[row];
            ushort* o = t1 + (size_t)row * H1D;
            o[lm]      = f2bf(acc0[r] * dv);
            o[16 + lm] = f2bf(acc1[r] * dv);
            o[32 + lm] = f2bf(acc2[r] * dv);
            o[48 + lm] = f2bf(acc3[r] * dv);
        }
    }
}

// ---------------- aggregation over 64-dim bf16 rows, one wave per node ----------------
// Paired gather: lane owns features (2c, 2c+1); half-wave 0 takes even edges,
// half-wave 1 odd edges; combine via shfl_xor(32).
// MODE 1: out = relu((dinv*sum)*sc + sv) * dinv     MODE 2: out = dinv*sum
template <int MODE>
__global__ __launch_bounds__(256) void agg64_k(const ushort* __restrict__ tin,
                                               ushort* __restrict__ tout,
                                               const int* __restrict__ rowstart,
                                               const int* __restrict__ csr,
                                               const float* __restrict__ dinv,
                                               const float* __restrict__ g,
                                               const float* __restrict__ bt,
                                               const float* __restrict__ rm,
                                               const float* __restrict__ rv,
                                               const float* __restrict__ b) {
    int wid = (blockIdx.x * blockDim.x + threadIdx.x) >> 6;
    int lane = threadIdx.x & 63;
    if (wid >= NN) return;
    int h = lane >> 5;       // half-wave
    int c = lane & 31;       // uint index: features 2c, 2c+1
    int rs = rowstart[wid], re = rowstart[wid + 1];
    float ax = 0.f, ay = 0.f;
    int i = rs;
    for (; i + 3 < re; i += 4) {
        int s0 = csr[i + h];
        int s1 = csr[i + 2 + h];
        uint v0 = *(const uint*)(tin + (size_t)s0 * H1D + 2 * c);
        uint v1 = *(const uint*)(tin + (size_t)s1 * H1D + 2 * c);
        ax += bf2f((ushort)(v0 & 0xffff)) + bf2f((ushort)(v1 & 0xffff));
        ay += bf2f((ushort)(v0 >> 16)) + bf2f((ushort)(v1 >> 16));
    }
    if (i + 1 < re) {
        int s = csr[i + h];
        uint v = *(const uint*)(tin + (size_t)s * H1D + 2 * c);
        ax += bf2f((ushort)(v & 0xffff));
        ay += bf2f((ushort)(v >> 16));
        i += 2;
    }
    if (i < re && h == 0) {
        int s = csr[i];
        uint v = *(const uint*)(tin + (size_t)s * H1D + 2 * c);
        ax += bf2f((ushort)(v & 0xffff));
        ay += bf2f((ushort)(v >> 16));
    }
    ax += __shfl_xor(ax, 32);
    ay += __shfl_xor(ay, 32);
    // self loop
    uint sv = *(const uint*)(tin + (size_t)wid * H1D + 2 * c);
    ax += bf2f((ushort)(sv & 0xffff));
    ay += bf2f((ushort)(sv >> 16));
    float dv = dinv[wid];
    float zx = ax * dv, zy = ay * dv;
    if (MODE == 1) {
        float2 gg = *(const float2*)(g + 2 * c);
        float2 vv = *(const float2*)(rv + 2 * c);
        float2 bb = *(const float2*)(b + 2 * c);
        float2 mm = *(const float2*)(rm + 2 * c);
        float2 tt = *(const float2*)(bt + 2 * c);
        float scx = gg.x * rsqrtf(vv.x + BNEPS);
        float scy = gg.y * rsqrtf(vv.y + BNEPS);
        zx = fmaxf(zx * scx + (bb.x - mm.x) * scx + tt.x, 0.f) * dv;
        zy = fmaxf(zy * scy + (bb.y - mm.y) * scy + tt.y, 0.f) * dv;
    }
    if (h == 0) {
        uint o = (uint)f2bf(zx) | ((uint)f2bf(zy) << 16);
        *(uint*)(tout + (size_t)wid * H1D + 2 * c) = o;
    }
}

// ---------------- fused GEMM2 + BN2 + ReLU + GEMM3 (bf16 in, bf16 padded out) ----------------
__global__ __launch_bounds__(256) void p2p3_k(const ushort* __restrict__ u2,
                                              const float* __restrict__ W2,
                                              const float* __restrict__ b2,
                                              const float* __restrict__ W3,
                                              const float* __restrict__ g2,
                                              const float* __restrict__ bt2,
                                              const float* __restrict__ rm2,
                                              const float* __restrict__ rv2,
                                              const float* __restrict__ dinv,
                                              ushort* __restrict__ g3) {
    __shared__ float sW2[H1D * H2D];
    __shared__ float sW3[H2D * CD];
    __shared__ float sc2[H2D], sh2[H2D];
    int tid = threadIdx.x;
    for (int i = tid; i < H1D * H2D; i += 256) sW2[i] = W2[i];
    for (int i = tid; i < H2D * CD; i += 256) sW3[i] = W3[i];
    if (tid < H2D) {
        float s = g2[tid] * rsqrtf(rv2[tid] + BNEPS);
        sc2[tid] = s;
        sh2[tid] = (b2[tid] - rm2[tid]) * s + bt2[tid];
    }
    __syncthreads();
    int node = blockIdx.x * 256 + tid;
    if (node >= NN) return;
    float u[H1D];
    const uint4* up = (const uint4*)(u2 + (size_t)node * H1D);
#pragma unroll
    for (int i = 0; i < 8; ++i) {
        uint4 v = up[i];
        u[8 * i + 0] = bf2f((ushort)(v.x & 0xffff)); u[8 * i + 1] = bf2f((ushort)(v.x >> 16));
        u[8 * i + 2] = bf2f((ushort)(v.y & 0xffff)); u[8 * i + 3] = bf2f((ushort)(v.y >> 16));
        u[8 * i + 4] = bf2f((ushort)(v.z & 0xffff)); u[8 * i + 5] = bf2f((ushort)(v.z >> 16));
        u[8 * i + 6] = bf2f((ushort)(v.w & 0xffff)); u[8 * i + 7] = bf2f((ushort)(v.w >> 16));
    }
    float gacc[CD];
#pragma unroll
    for (int c = 0; c < CD; ++c) gacc[c] = 0.f;
    for (int fc = 0; fc < H2D; fc += 32) {
        float a[32];
#pragma unroll
        for (int j = 0; j < 32; ++j) a[j] = 0.f;
        for (int l = 0; l < H1D; ++l) {
            float ul = u[l];
            const float4* wr = (const float4*)&sW2[l * H2D + fc];
#pragma unroll
            for (int j = 0; j < 8; ++j) {
                float4 w = wr[j];
                a[4 * j]     += ul * w.x;
                a[4 * j + 1] += ul * w.y;
                a[4 * j + 2] += ul * w.z;
                a[4 * j + 3] += ul * w.w;
            }
        }
#pragma unroll
        for (int j = 0; j < 32; ++j) {
            int f = fc + j;
            float hv = fmaxf(a[j] * sc2[f] + sh2[f], 0.f);
            const float4* w3r = (const float4*)&sW3[f * CD];
#pragma unroll
            for (int c = 0; c < 10; ++c) {
                float4 w = w3r[c];
                gacc[4 * c]     += hv * w.x;
                gacc[4 * c + 1] += hv * w.y;
                gacc[4 * c + 2] += hv * w.z;
                gacc[4 * c + 3] += hv * w.w;
            }
        }
    }
    float dv = dinv[node];
    ushort* op = g3 + (size_t)node * GP;
#pragma unroll
    for (int c = 0; c < 10; ++c) {
        uint pk  = (uint)f2bf(gacc[4 * c] * dv)     | ((uint)f2bf(gacc[4 * c + 1] * dv) << 16);
        uint pk2 = (uint)f2bf(gacc[4 * c + 2] * dv) | ((uint)f2bf(gacc[4 * c + 3] * dv) << 16);
        *(uint2*)&op[4 * c] = make_uint2(pk, pk2);
    }
    // zero the pad (cols 40..63) so agg40 pad reads are exact zeros
    *(uint2*)&op[40] = make_uint2(0u, 0u);
    *(uint2*)&op[44] = make_uint2(0u, 0u);
    *(uint2*)&op[48] = make_uint2(0u, 0u);
    *(uint2*)&op[52] = make_uint2(0u, 0u);
    *(uint2*)&op[56] = make_uint2(0u, 0u);
    *(uint2*)&op[60] = make_uint2(0u, 0u);
}

// ---------------- aggregation over padded 40-dim bf16 + bias + log_softmax ----------------
__global__ __launch_bounds__(256) void agg40_k(const ushort* __restrict__ g3,
                                               const float* __restrict__ b3,
                                               const int* __restrict__ rowstart,
                                               const int* __restrict__ csr,
                                               const float* __restrict__ dinv,
                                               float* __restrict__ out) {
    int wid = (blockIdx.x * blockDim.x + threadIdx.x) >> 6;
    int lane = threadIdx.x & 63;
    if (wid >= NN) return;
    int h = lane >> 5;
    int c = lane & 31;       // features 2c, 2c+1 (pad beyond 40 is zero)
    int rs = rowstart[wid], re = rowstart[wid + 1];
    float ax = 0.f, ay = 0.f;
    int i = rs;
    for (; i + 3 < re; i += 4) {
        int s0 = csr[i + h];
        int s1 = csr[i + 2 + h];
        uint v0 = *(const uint*)(g3 + (size_t)s0 * GP + 2 * c);
        uint v1 = *(const uint*)(g3 + (size_t)s1 * GP + 2 * c);
        ax += bf2f((ushort)(v0 & 0xffff)) + bf2f((ushort)(v1 & 0xffff));
        ay += bf2f((ushort)(v0 >> 16)) + bf2f((ushort)(v1 >> 16));
    }
    if (i + 1 < re) {
        int s = csr[i + h];
        uint v = *(const uint*)(g3 + (size_t)s * GP + 2 * c);
        ax += bf2f((ushort)(v & 0xffff));
        ay += bf2f((ushort)(v >> 16));
        i += 2;
    }
    if (i < re && h == 0) {
        int s = csr[i];
        uint v = *(const uint*)(g3 + (size_t)s * GP + 2 * c);
        ax += bf2f((ushort)(v & 0xffff));
        ay += bf2f((ushort)(v >> 16));
    }
    ax += __shfl_xor(ax, 32);
    ay += __shfl_xor(ay, 32);
    uint sv = *(const uint*)(g3 + (size_t)wid * GP + 2 * c);
    ax += bf2f((ushort)(sv & 0xffff));
    ay += bf2f((ushort)(sv >> 16));
    float dv = dinv[wid];
    float zx, zy;
    if (2 * c < CD) {
        float2 bb = *(const float2*)(b3 + 2 * c);
        zx = ax * dv + bb.x;
        zy = ay * dv + bb.y;
    } else {
        zx = -1e30f; zy = -1e30f;
    }
    float m = fmaxf(zx, zy);
#pragma unroll
    for (int off = 16; off > 0; off >>= 1) m = fmaxf(m, __shfl_xor(m, off));
    float e = (2 * c < CD) ? (__expf(zx - m) + __expf(zy - m)) : 0.f;
#pragma unroll
    for (int off = 16; off > 0; off >>= 1) e += __shfl_xor(e, off);
    if (h == 0 && 2 * c < CD) {
        float ls = __logf(e);
        float2 o = { zx - m - ls, zy - m - ls };
        *(float2*)(out + (size_t)wid * CD + 2 * c) = o;
    }
}

// ---------------- launcher ----------------

extern "C" void kernel_launch(void* const* d_in, const int* in_sizes, int n_in,
                              void* d_out, int out_size, void* d_ws, size_t ws_size,
                              hipStream_t stream) {
    (void)n_in; (void)out_size; (void)ws_size;
    const float* x   = (const float*)d_in[0];
    const int*   ei  = (const int*)d_in[1];
    const float* W1  = (const float*)d_in[2];
    const float* b1  = (const float*)d_in[3];
    const float* W2  = (const float*)d_in[4];
    const float* b2  = (const float*)d_in[5];
    const float* W3  = (const float*)d_in[6];
    const float* b3  = (const float*)d_in[7];
    const float* g1  = (const float*)d_in[8];
    const float* bt1 = (const float*)d_in[9];
    const float* rm1 = (const float*)d_in[10];
    const float* rv1 = (const float*)d_in[11];
    const float* g2  = (const float*)d_in[12];
    const float* bt2 = (const float*)d_in[13];
    const float* rm2 = (const float*)d_in[14];
    const float* rv2 = (const float*)d_in[15];
    float* out = (float*)d_out;
    const int E = in_sizes[1] / 2;

    char* w = (char*)d_ws;
    auto alloc = [&](size_t bytes) { char* p = w; w += (bytes + 511) & ~(size_t)511; return p; };
    int*    bcount   = (int*)alloc((size_t)NB * 4);
    int*    bstart   = (int*)alloc((size_t)(NB + 1) * 4);
    int*    bcursor  = (int*)alloc((size_t)NB * 4);
    int*    rowstart = (int*)alloc((size_t)(NN + 1) * 4);
    float*  dinv     = (float*)alloc((size_t)NN * 4);
    int*    csr      = (int*)alloc((size_t)E * 4);
    int*    ebuf     = (int*)alloc((size_t)E * 4);
    ushort* w1t      = (ushort*)alloc((size_t)H1D * FIN * 2);
    ushort* t1       = (ushort*)alloc((size_t)NN * H1D * 2);  // reused as u2
    ushort* t2       = (ushort*)alloc((size_t)NN * H1D * 2);
    ushort* g3       = (ushort*)alloc((size_t)NN * GP * 2);

    hipMemsetAsync(bcount, 0, (size_t)NB * 4, stream);
    bhist_k<<<512, 256, 0, stream>>>(ei + E, E, bcount);
    bscan_k<<<1, 256, 0, stream>>>(bcount, bstart, bcursor);
    bscatter_k<<<(E + CHUNK - 1) / CHUNK, 256, 0, stream>>>(ei, ei + E, E, bcursor, ebuf);
    bcsr_k<<<NB, 256, 0, stream>>>(ebuf, bstart, rowstart, dinv, csr, E);
    w1cvt_k<<<(FIN * H1D + 255) / 256, 256, 0, stream>>>(W1, w1t);
    gemm1_k<<<(NN + 63) / 64, 256, 0, stream>>>(x, w1t, dinv, t1);
    agg64_k<1><<<(NN + 3) / 4, 256, 0, stream>>>(t1, t2, rowstart, csr, dinv, g1, bt1, rm1, rv1, b1);
    agg64_k<2><<<(NN + 3) / 4, 256, 0, stream>>>(t2, t1, rowstart, csr, dinv, nullptr, nullptr, nullptr, nullptr, nullptr);
    p2p3_k<<<(NN + 255) / 256, 256, 0, stream>>>(t1, W2, b2, W3, g2, bt2, rm2, rv2, dinv, g3);
    agg40_k<<<(NN + 3) / 4, 256, 0, stream>>>(g3, b3, rowstart, csr, dinv, out);
}